// Round 3
// baseline (27272.357 us; speedup 1.0000x reference)
//
#include <hip/hip_runtime.h>
#include <math.h>

#define T_ 512
#define B_ 64
#define IN_ 128
#define H_ 512
#define L_ 3
#define OUT_ 128

typedef _Float16 half2_t __attribute__((ext_vector_type(2)));

#if defined(__has_builtin)
#if __has_builtin(__builtin_amdgcn_fdot2)
#define HAVE_FDOT2 1
#endif
#endif

__device__ __forceinline__ float fdot2_acc(half2_t a, half2_t b, float c) {
#ifdef HAVE_FDOT2
    return __builtin_amdgcn_fdot2(a, b, c, false);
#else
    return c + (float)a.x * (float)b.x + (float)a.y * (float)b.y;
#endif
}

// ---- workspace layout (floats) ----
constexpr size_t OFF_BUF = 0;                            // T*B*H = 16,777,216 floats
constexpr size_t OFF_WHP = (size_t)T_ * B_ * H_;         // fp16-packed W_hh: 3*256*512 dwords (1.5MB)
constexpr size_t OFF_WTI = OFF_WHP + 3ull * 256 * H_;    // 2 * H*H (W_ih_rest^T, fp32)
constexpr size_t OFF_WT0 = OFF_WTI + 2ull * H_ * H_;     // IN*H   (W_ih0^T)
constexpr size_t OFF_WTL = OFF_WT0 + (size_t)IN_ * H_;   // H*OUT  (lin_W^T)
// total ≈ 17.8M floats ≈ 68 MB

// Batched transpose for the GEMM weights: dst[c*R + r] = src[r*C + c]
__global__ void transpose_all(const float* __restrict__ wihr,
                              const float* __restrict__ wih0,
                              const float* __restrict__ linw,
                              float* __restrict__ ws) {
    __shared__ float tile[32][33];
    const float* src; float* dst; int R, C;
    switch (blockIdx.z) {
        case 0: case 1: {
            int l = blockIdx.z;
            src = wihr + (size_t)l * H_ * H_;
            dst = ws + OFF_WTI + (size_t)l * H_ * H_;
            R = H_; C = H_; break;
        }
        case 2:
            src = wih0; dst = ws + OFF_WT0; R = H_; C = IN_; break;  // -> [IN][H]
        default:
            src = linw; dst = ws + OFF_WTL; R = OUT_; C = H_; break; // -> [H][OUT]
    }
    int bx = blockIdx.x * 32;
    int by = blockIdx.y * 32;
    if (bx >= C || by >= R) return;
    for (int i = threadIdx.y; i < 32; i += 8) {
        int r = by + i, c = bx + threadIdx.x;
        if (r < R && c < C) tile[i][threadIdx.x] = src[(size_t)r * C + c];
    }
    __syncthreads();
    for (int i = threadIdx.y; i < 32; i += 8) {
        int c = bx + i, r = by + threadIdx.x;
        if (r < R && c < C) dst[(size_t)c * R + r] = tile[threadIdx.x][i];
    }
}

// Pack W_hh (fp32 [l][j][k]) -> Wp dwords [l][kp][j] = (half(W[j][2kp]), half(W[j][2kp+1]))
// RNE conversion for accuracy. Writes coalesced over j.
__global__ __launch_bounds__(512) void pack_whh(const float* __restrict__ whh,
                                                unsigned int* __restrict__ Wp) {
    const int l = blockIdx.x >> 8;
    const int kp = blockIdx.x & 255;
    const int j = threadIdx.x;
    const float* s = whh + ((size_t)l * H_ + j) * H_ + 2 * kp;
    union { half2_t h; unsigned int u; } cv;
    cv.h.x = (_Float16)s[0];
    cv.h.y = (_Float16)s[1];
    Wp[((size_t)l * 256 + kp) * H_ + j] = cv.u;
}

// Row-panel GEMM: Out[m][j] = sum_k In[m][k] * Wt[k][j] + bias[j]  (fp32, unchanged)
template <int N, int K>
__global__ __launch_bounds__(512) void gemm_panel(const float* In,
                                                  const float* __restrict__ Wt,
                                                  const float* __restrict__ bias,
                                                  float* Out) {
    __shared__ float A[16 * K];
    const int tid = threadIdx.x;
    const size_t m0 = (size_t)blockIdx.x * 16;

    const float4* In4 = (const float4*)(In + m0 * K);
    float4* A4 = (float4*)A;
    for (int i = tid; i < 16 * K / 4; i += 512) A4[i] = In4[i];
    __syncthreads();

    constexpr int TPN = 512 / N;
    constexpr int RPT = 16 / TPN;
    const int j = tid % N;
    const int r0 = (tid / N) * RPT;

    float acc[RPT];
    const float bv = bias[j];
    #pragma unroll
    for (int r = 0; r < RPT; r++) acc[r] = bv;

    for (int k = 0; k < K; k += 4) {
        const float wv0 = Wt[(size_t)(k + 0) * N + j];
        const float wv1 = Wt[(size_t)(k + 1) * N + j];
        const float wv2 = Wt[(size_t)(k + 2) * N + j];
        const float wv3 = Wt[(size_t)(k + 3) * N + j];
        #pragma unroll
        for (int r = 0; r < RPT; r++) {
            const float4 av = *(const float4*)&A[(r0 + r) * K + k];
            acc[r] += av.x * wv0 + av.y * wv1 + av.z * wv2 + av.w * wv3;
        }
    }
    #pragma unroll
    for (int r = 0; r < RPT; r++) Out[(m0 + r0 + r) * N + j] = acc[r];
}

// Recurrence: one block (1024 threads, 16 waves) per batch row.
// Wave w owns k in [32w, 32w+32); lane l owns j in [8l, 8l+8).
// Weights: fp16 pairs, dword layout Wp[kp][j] -> coalesced dwordx4 loads.
// h: fp32 in LDS, broadcast reads. Partials reduced via LDS red[16][512].
__global__ __launch_bounds__(1024) void rnn_rec2(float* __restrict__ buf,
                                                 const unsigned int* __restrict__ Wp, // [256][512]
                                                 const float* __restrict__ h0_l,
                                                 const float* __restrict__ bhh,
                                                 float* __restrict__ hout) {
    __shared__ __align__(16) float hsm[H_];        // 2 KB
    __shared__ __align__(16) float red[16][H_];    // 32 KB
    const int b   = blockIdx.x;
    const int tid = threadIdx.x;
    const int w   = tid >> 6;
    const int ln  = tid & 63;

    for (int i = tid; i < H_; i += 1024) hsm[i] = h0_l[b * H_ + i];
    const float bj = (tid < H_) ? bhh[tid] : 0.f;
    __syncthreads();

    const unsigned int* wbase = Wp + (size_t)(w * 16) * H_ + ln * 8;

    for (int t = 0; t < T_; t++) {
        // prefetch pre-activation for this step (consumed after barrier; hides L3 latency)
        float pre = 0.f;
        if (tid < H_) pre = buf[((size_t)t * B_ + b) * H_ + tid];

        // build this wave's 16 h-pairs (broadcast LDS reads, RNE converts)
        half2_t hp[16];
        const float4* hq = (const float4*)(hsm + w * 32);
        #pragma unroll
        for (int q = 0; q < 8; q++) {
            float4 v = hq[q];
            hp[2 * q].x     = (_Float16)v.x;
            hp[2 * q].y     = (_Float16)v.y;
            hp[2 * q + 1].x = (_Float16)v.z;
            hp[2 * q + 1].y = (_Float16)v.w;
        }

        float acc[8] = {0.f, 0.f, 0.f, 0.f, 0.f, 0.f, 0.f, 0.f};
        const unsigned int* p = wbase;
        #pragma unroll 4
        for (int kp = 0; kp < 16; kp++) {
            const uint4 w0 = *(const uint4*)p;
            const uint4 w1 = *(const uint4*)(p + 4);
            union { unsigned int u; half2_t h; } c0, c1, c2, c3, c4, c5, c6, c7;
            c0.u = w0.x; c1.u = w0.y; c2.u = w0.z; c3.u = w0.w;
            c4.u = w1.x; c5.u = w1.y; c6.u = w1.z; c7.u = w1.w;
            const half2_t hv = hp[kp];
            acc[0] = fdot2_acc(c0.h, hv, acc[0]);
            acc[1] = fdot2_acc(c1.h, hv, acc[1]);
            acc[2] = fdot2_acc(c2.h, hv, acc[2]);
            acc[3] = fdot2_acc(c3.h, hv, acc[3]);
            acc[4] = fdot2_acc(c4.h, hv, acc[4]);
            acc[5] = fdot2_acc(c5.h, hv, acc[5]);
            acc[6] = fdot2_acc(c6.h, hv, acc[6]);
            acc[7] = fdot2_acc(c7.h, hv, acc[7]);
            p += H_;
        }

        // write partial sums (vector, conflict-light)
        *(float4*)&red[w][ln * 8]     = make_float4(acc[0], acc[1], acc[2], acc[3]);
        *(float4*)&red[w][ln * 8 + 4] = make_float4(acc[4], acc[5], acc[6], acc[7]);
        __syncthreads();   // all hsm reads + red writes done

        if (tid < H_) {
            float s = pre + bj;
            #pragma unroll
            for (int q = 0; q < 16; q++) s += red[q][tid];
            const float hn = tanhf(s);
            hsm[tid] = hn;                                  // safe: reads finished pre-barrier
            buf[((size_t)t * B_ + b) * H_ + tid] = hn;
        }
        __syncthreads();   // h ready for next step
    }
    if (tid < H_) hout[b * H_ + tid] = hsm[tid];
}

extern "C" void kernel_launch(void* const* d_in, const int* in_sizes, int n_in,
                              void* d_out, int out_size, void* d_ws, size_t ws_size,
                              hipStream_t stream) {
    const float* x      = (const float*)d_in[0];
    const float* h0     = (const float*)d_in[1];
    const float* W_ih0  = (const float*)d_in[2];
    const float* W_ihr  = (const float*)d_in[3];
    const float* W_hh   = (const float*)d_in[4];
    const float* b_ih   = (const float*)d_in[5];
    const float* b_hh   = (const float*)d_in[6];
    const float* lin_W  = (const float*)d_in[7];
    const float* lin_b  = (const float*)d_in[8];
    float* out = (float*)d_out;
    float* ws  = (float*)d_ws;

    float* buf = ws + OFF_BUF;
    unsigned int* Wp = (unsigned int*)(ws + OFF_WHP);
    float* WtI = ws + OFF_WTI;
    float* Wt0 = ws + OFF_WT0;
    float* WtL = ws + OFF_WTL;
    float* h_final = out + (size_t)T_ * B_ * OUT_;  // [L][B][H]

    constexpr int M = T_ * B_;  // 32768 rows

    // 1) prep: transpose GEMM weights (fp32) + pack W_hh to fp16 pairs
    transpose_all<<<dim3(16, 16, 4), dim3(32, 8), 0, stream>>>(W_ihr, W_ih0, lin_W, ws);
    pack_whh<<<3 * 256, 512, 0, stream>>>(W_hh, Wp);

    // 2) layer 0
    gemm_panel<H_, IN_><<<M / 16, 512, 0, stream>>>(x, Wt0, b_ih + 0 * H_, buf);
    rnn_rec2<<<B_, 1024, 0, stream>>>(buf, Wp + 0ull * 256 * H_, h0 + 0 * B_ * H_,
                                      b_hh + 0 * H_, h_final + 0 * B_ * H_);

    // 3) layer 1
    gemm_panel<H_, H_><<<M / 16, 512, 0, stream>>>(buf, WtI + 0 * (size_t)H_ * H_,
                                                   b_ih + 1 * H_, buf);
    rnn_rec2<<<B_, 1024, 0, stream>>>(buf, Wp + 1ull * 256 * H_, h0 + 1 * B_ * H_,
                                      b_hh + 1 * H_, h_final + 1 * B_ * H_);

    // 4) layer 2
    gemm_panel<H_, H_><<<M / 16, 512, 0, stream>>>(buf, WtI + 1 * (size_t)H_ * H_,
                                                   b_ih + 2 * H_, buf);
    rnn_rec2<<<B_, 1024, 0, stream>>>(buf, Wp + 2ull * 256 * H_, h0 + 2 * B_ * H_,
                                      b_hh + 2 * H_, h_final + 2 * B_ * H_);

    // 5) out = ys2 @ lin_W^T + lin_b
    gemm_panel<OUT_, H_><<<M / 16, 512, 0, stream>>>(buf, WtL, lin_b, out);
}

// Round 4
// 19919.427 us; speedup vs baseline: 1.3691x; 1.3691x over previous
//
#include <hip/hip_runtime.h>
#include <math.h>

#define T_ 512
#define B_ 64
#define IN_ 128
#define H_ 512
#define L_ 3
#define OUT_ 128

typedef _Float16 half2_t __attribute__((ext_vector_type(2)));

#if defined(__has_builtin)
#if __has_builtin(__builtin_amdgcn_fdot2)
#define HAVE_FDOT2 1
#endif
#endif

__device__ __forceinline__ float fdot2_acc(half2_t a, half2_t b, float c) {
#ifdef HAVE_FDOT2
    return __builtin_amdgcn_fdot2(a, b, c, false);
#else
    return c + (float)a.x * (float)b.x + (float)a.y * (float)b.y;
#endif
}

union HU { unsigned int u; half2_t h; };

// ---- workspace layout (floats) ----
constexpr size_t OFF_BUF   = 0;                              // T*B*H
constexpr size_t OFF_WHP   = (size_t)T_ * B_ * H_;           // 3*256*512 dwords
constexpr size_t OFF_WTI   = OFF_WHP + 3ull * 256 * H_;      // 2*H*H fp32
constexpr size_t OFF_WT0   = OFF_WTI + 2ull * H_ * H_;       // IN*H
constexpr size_t OFF_WTL   = OFF_WT0 + (size_t)IN_ * H_;     // H*OUT
constexpr size_t OFF_HX    = OFF_WTL + (size_t)H_ * OUT_;    // 128*256 exchange
constexpr size_t OFF_FLAGS = OFF_HX + 128ull * 256;          // 128 uints

// Batched transpose for the GEMM weights: dst[c*R + r] = src[r*C + c]
__global__ void transpose_all(const float* __restrict__ wihr,
                              const float* __restrict__ wih0,
                              const float* __restrict__ linw,
                              float* __restrict__ ws) {
    __shared__ float tile[32][33];
    const float* src; float* dst; int R, C;
    switch (blockIdx.z) {
        case 0: case 1: {
            int l = blockIdx.z;
            src = wihr + (size_t)l * H_ * H_;
            dst = ws + OFF_WTI + (size_t)l * H_ * H_;
            R = H_; C = H_; break;
        }
        case 2:
            src = wih0; dst = ws + OFF_WT0; R = H_; C = IN_; break;  // -> [IN][H]
        default:
            src = linw; dst = ws + OFF_WTL; R = OUT_; C = H_; break; // -> [H][OUT]
    }
    int bx = blockIdx.x * 32;
    int by = blockIdx.y * 32;
    if (bx >= C || by >= R) return;
    for (int i = threadIdx.y; i < 32; i += 8) {
        int r = by + i, c = bx + threadIdx.x;
        if (r < R && c < C) tile[i][threadIdx.x] = src[(size_t)r * C + c];
    }
    __syncthreads();
    for (int i = threadIdx.y; i < 32; i += 8) {
        int c = bx + i, r = by + threadIdx.x;
        if (r < R && c < C) dst[(size_t)c * R + r] = tile[threadIdx.x][i];
    }
}

// Pack W_hh (fp32 [l][j][k]) -> Wp dwords [l][kp][j] = half2(W[j][2kp], W[j][2kp+1]), RNE.
__global__ __launch_bounds__(512) void pack_whh(const float* __restrict__ whh,
                                                unsigned int* __restrict__ Wp) {
    const int l = blockIdx.x >> 8;
    const int kp = blockIdx.x & 255;
    const int j = threadIdx.x;
    const float* s = whh + ((size_t)l * H_ + j) * H_ + 2 * kp;
    HU cv;
    cv.h.x = (_Float16)s[0];
    cv.h.y = (_Float16)s[1];
    Wp[((size_t)l * 256 + kp) * H_ + j] = cv.u;
}

// Row-panel GEMM (fp32), unchanged from R2/R3 (verified). In-place safe.
template <int N, int K>
__global__ __launch_bounds__(512) void gemm_panel(const float* In,
                                                  const float* __restrict__ Wt,
                                                  const float* __restrict__ bias,
                                                  float* Out) {
    __shared__ float A[16 * K];
    const int tid = threadIdx.x;
    const size_t m0 = (size_t)blockIdx.x * 16;

    const float4* In4 = (const float4*)(In + m0 * K);
    float4* A4 = (float4*)A;
    for (int i = tid; i < 16 * K / 4; i += 512) A4[i] = In4[i];
    __syncthreads();

    constexpr int TPN = 512 / N;
    constexpr int RPT = 16 / TPN;
    const int j = tid % N;
    const int r0 = (tid / N) * RPT;

    float acc[RPT];
    const float bv = bias[j];
    #pragma unroll
    for (int r = 0; r < RPT; r++) acc[r] = bv;

    for (int k = 0; k < K; k += 4) {
        const float wv0 = Wt[(size_t)(k + 0) * N + j];
        const float wv1 = Wt[(size_t)(k + 1) * N + j];
        const float wv2 = Wt[(size_t)(k + 2) * N + j];
        const float wv3 = Wt[(size_t)(k + 3) * N + j];
        #pragma unroll
        for (int r = 0; r < RPT; r++) {
            const float4 av = *(const float4*)&A[(r0 + r) * K + k];
            acc[r] += av.x * wv0 + av.y * wv1 + av.z * wv2 + av.w * wv3;
        }
    }
    #pragma unroll
    for (int r = 0; r < RPT; r++) Out[(m0 + r0 + r) * N + j] = acc[r];
}

// Recurrence: 128 blocks x 512 threads. Block (half, b) with blockIdx = b + 64*half
// owns j in [half*256, half*256+256) with W_hh^T half RESIDENT IN REGISTERS.
// Per step: pure-VALU MAC -> LDS k-reduce -> tanh -> publish own 256 h's via
// agent-scope atomics + flag; spin on partner flag; import partner h's.
__global__ __launch_bounds__(512) void rnn_rec3(float* __restrict__ buf,
                                                const unsigned int* __restrict__ Wp, // [256][512] this layer
                                                const float* __restrict__ h0_l,      // [B][H]
                                                const float* __restrict__ bhh,       // [H]
                                                float* __restrict__ hout,            // [B][H]
                                                float* __restrict__ hx,              // [128][256]
                                                unsigned int* __restrict__ flags,    // [128]
                                                int flagbase) {
    __shared__ unsigned int hsm2[256];     // h as packed half2 (1 KB); half-view: h[j']
    __shared__ float4 red4[16 * 64];       // 16 KB, XOR-swizzled k-partials

    const int tid  = threadIdx.x;
    const int w    = tid >> 6;
    const int ln   = tid & 63;
    const int half = blockIdx.x >> 6;
    const int b    = blockIdx.x & 63;
    const int jo   = ln & 31;              // j-octet within my 256-half
    const int kh   = ln >> 5;
    const int r    = w * 2 + kh;           // reduction row 0..15
    const int jbase  = half * 256 + jo * 8;  // global j of my octet
    const int kpbase = w * 32 + kh * 16;     // my 16 h-pair indices

    // ---- load my weight tile into registers: 8 j x 32 k = 32 uint4 ----
    uint4 wreg[32];
    {
        const uint4* wp4 = (const uint4*)(Wp + (size_t)kpbase * H_ + jbase);
        #pragma unroll
        for (int kp = 0; kp < 16; ++kp) {
            wreg[2 * kp + 0] = wp4[kp * (H_ / 4) + 0];
            wreg[2 * kp + 1] = wp4[kp * (H_ / 4) + 1];
        }
    }

    // ---- h(0) ----
    if (tid < 256) {
        const float2 v = *(const float2*)(h0_l + b * H_ + 2 * tid);
        HU cv; cv.h.x = (_Float16)v.x; cv.h.y = (_Float16)v.y;
        hsm2[tid] = cv.u;
    }
    const float bj = (tid < 256) ? bhh[half * 256 + tid] : 0.f;
    float* myhx = hx + (size_t)blockIdx.x * 256;
    const float* phx = hx + (size_t)(blockIdx.x ^ 64) * 256;
    __syncthreads();

    for (int t = 0; t < T_; ++t) {
        // prefetch pre-activation (consumed after bar1)
        float pre = 0.f;
        if (tid < 256) pre = buf[((size_t)t * B_ + b) * H_ + half * 256 + tid];

        // broadcast-read my 16 h-pairs
        unsigned int hp[16];
        {
            const uint4* hq = (const uint4*)&hsm2[kpbase];
            #pragma unroll
            for (int q = 0; q < 4; ++q) {
                const uint4 hv = hq[q];
                hp[4 * q + 0] = hv.x; hp[4 * q + 1] = hv.y;
                hp[4 * q + 2] = hv.z; hp[4 * q + 3] = hv.w;
            }
        }

        // pure-register MAC: 128 fdot2
        float acc[8] = {0.f, 0.f, 0.f, 0.f, 0.f, 0.f, 0.f, 0.f};
        #pragma unroll
        for (int kp = 0; kp < 16; ++kp) {
            HU hv; hv.u = hp[kp];
            HU w0, w1, w2, w3, w4, w5, w6, w7;
            w0.u = wreg[2 * kp].x;     w1.u = wreg[2 * kp].y;
            w2.u = wreg[2 * kp].z;     w3.u = wreg[2 * kp].w;
            w4.u = wreg[2 * kp + 1].x; w5.u = wreg[2 * kp + 1].y;
            w6.u = wreg[2 * kp + 1].z; w7.u = wreg[2 * kp + 1].w;
            acc[0] = fdot2_acc(w0.h, hv.h, acc[0]);
            acc[1] = fdot2_acc(w1.h, hv.h, acc[1]);
            acc[2] = fdot2_acc(w2.h, hv.h, acc[2]);
            acc[3] = fdot2_acc(w3.h, hv.h, acc[3]);
            acc[4] = fdot2_acc(w4.h, hv.h, acc[4]);
            acc[5] = fdot2_acc(w5.h, hv.h, acc[5]);
            acc[6] = fdot2_acc(w6.h, hv.h, acc[6]);
            acc[7] = fdot2_acc(w7.h, hv.h, acc[7]);
        }

        // swizzled partial writes (bank-spread verified)
        {
            const int s  = (jo >> 2) & 7;
            const int f0 = (jo * 2 + 0) ^ s;
            const int f1 = (jo * 2 + 1) ^ s;
            red4[r * 64 + f0] = make_float4(acc[0], acc[1], acc[2], acc[3]);
            red4[r * 64 + f1] = make_float4(acc[4], acc[5], acc[6], acc[7]);
        }
        __syncthreads();  // bar1: partials ready

        if (tid < 256) {
            const float* redf = (const float*)red4;
            const int f4 = (tid >> 2) ^ ((tid >> 5) & 7);
            const int e  = tid & 3;
            float s = pre + bj;
            #pragma unroll
            for (int q = 0; q < 16; ++q) s += redf[(q * 64 + f4) * 4 + e];
            const float hn = tanhf(s);
            const int jg = half * 256 + tid;
            buf[((size_t)t * B_ + b) * H_ + jg] = hn;
            __hip_atomic_store(&myhx[tid], hn, __ATOMIC_RELAXED, __HIP_MEMORY_SCOPE_AGENT);
            ((_Float16*)hsm2)[jg] = (_Float16)hn;          // own half -> LDS (b16)
            if (t == T_ - 1) hout[b * H_ + jg] = hn;
            __threadfence();
        }
        __syncthreads();  // bar2: red consumed + all hx stores drained (per-wave vmcnt)

        const unsigned int want = (unsigned int)(flagbase + t + 1);
        if (tid == 0) {
            __hip_atomic_store(&flags[blockIdx.x], want, __ATOMIC_RELEASE, __HIP_MEMORY_SCOPE_AGENT);
            while (__hip_atomic_load(&flags[blockIdx.x ^ 64], __ATOMIC_ACQUIRE,
                                     __HIP_MEMORY_SCOPE_AGENT) < want) { }
        }
        __syncthreads();  // bar3: partner published

        if (tid < 256) {
            const float hv = __hip_atomic_load(&phx[tid], __ATOMIC_RELAXED, __HIP_MEMORY_SCOPE_AGENT);
            ((_Float16*)hsm2)[(half ^ 1) * 256 + tid] = (_Float16)hv;  // partner half -> LDS
        }
        __syncthreads();  // bar4: full h ready for next step
    }
}

extern "C" void kernel_launch(void* const* d_in, const int* in_sizes, int n_in,
                              void* d_out, int out_size, void* d_ws, size_t ws_size,
                              hipStream_t stream) {
    const float* x      = (const float*)d_in[0];
    const float* h0     = (const float*)d_in[1];
    const float* W_ih0  = (const float*)d_in[2];
    const float* W_ihr  = (const float*)d_in[3];
    const float* W_hh   = (const float*)d_in[4];
    const float* b_ih   = (const float*)d_in[5];
    const float* b_hh   = (const float*)d_in[6];
    const float* lin_W  = (const float*)d_in[7];
    const float* lin_b  = (const float*)d_in[8];
    float* out = (float*)d_out;
    float* ws  = (float*)d_ws;

    float* buf = ws + OFF_BUF;
    unsigned int* Wp = (unsigned int*)(ws + OFF_WHP);
    float* WtI = ws + OFF_WTI;
    float* Wt0 = ws + OFF_WT0;
    float* WtL = ws + OFF_WTL;
    float* hx  = ws + OFF_HX;
    unsigned int* flags = (unsigned int*)(ws + OFF_FLAGS);
    float* h_final = out + (size_t)T_ * B_ * OUT_;  // [L][B][H]

    constexpr int M = T_ * B_;  // 32768 rows

    // 0) zero the pair-sync flags (ws is poisoned 0xAA before every call)
    hipMemsetAsync(flags, 0, 128 * sizeof(unsigned int), stream);

    // 1) prep: transpose GEMM weights (fp32) + pack W_hh to fp16 pairs
    transpose_all<<<dim3(16, 16, 4), dim3(32, 8), 0, stream>>>(W_ihr, W_ih0, lin_W, ws);
    pack_whh<<<3 * 256, 512, 0, stream>>>(W_hh, Wp);

    // 2) layer 0
    gemm_panel<H_, IN_><<<M / 16, 512, 0, stream>>>(x, Wt0, b_ih + 0 * H_, buf);
    rnn_rec3<<<128, 512, 0, stream>>>(buf, Wp + 0ull * 256 * H_, h0 + 0 * B_ * H_,
                                      b_hh + 0 * H_, h_final + 0 * B_ * H_,
                                      hx, flags, 0 * T_);

    // 3) layer 1
    gemm_panel<H_, H_><<<M / 16, 512, 0, stream>>>(buf, WtI + 0 * (size_t)H_ * H_,
                                                   b_ih + 1 * H_, buf);
    rnn_rec3<<<128, 512, 0, stream>>>(buf, Wp + 1ull * 256 * H_, h0 + 1 * B_ * H_,
                                      b_hh + 1 * H_, h_final + 1 * B_ * H_,
                                      hx, flags, 1 * T_);

    // 4) layer 2
    gemm_panel<H_, H_><<<M / 16, 512, 0, stream>>>(buf, WtI + 1 * (size_t)H_ * H_,
                                                   b_ih + 2 * H_, buf);
    rnn_rec3<<<128, 512, 0, stream>>>(buf, Wp + 2ull * 256 * H_, h0 + 2 * B_ * H_,
                                      b_hh + 2 * H_, h_final + 2 * B_ * H_,
                                      hx, flags, 2 * T_);

    // 5) out = ys2 @ lin_W^T + lin_b
    gemm_panel<OUT_, H_><<<M / 16, 512, 0, stream>>>(buf, WtL, lin_b, out);
}

// Round 5
// 3424.479 us; speedup vs baseline: 7.9639x; 5.8168x over previous
//
#include <hip/hip_runtime.h>
#include <math.h>

#define T_ 512
#define B_ 64
#define IN_ 128
#define H_ 512
#define L_ 3
#define OUT_ 128

typedef _Float16 half2_t __attribute__((ext_vector_type(2)));

#if defined(__has_builtin)
#if __has_builtin(__builtin_amdgcn_fdot2)
#define HAVE_FDOT2 1
#endif
#endif

__device__ __forceinline__ float fdot2_acc(half2_t a, half2_t b, float c) {
#ifdef HAVE_FDOT2
    return __builtin_amdgcn_fdot2(a, b, c, false);
#else
    return c + (float)a.x * (float)b.x + (float)a.y * (float)b.y;
#endif
}

union HU { unsigned int u; half2_t h; };

// ---- workspace layout (floats) ----
constexpr size_t OFF_BUF = 0;                            // T*B*H
constexpr size_t OFF_WHP = (size_t)T_ * B_ * H_;         // 3*256*512 dwords (fp16 pairs)
constexpr size_t OFF_WTI = OFF_WHP + 3ull * 256 * H_;    // 2*H*H fp32
constexpr size_t OFF_WT0 = OFF_WTI + 2ull * H_ * H_;     // IN*H
constexpr size_t OFF_WTL = OFF_WT0 + (size_t)IN_ * H_;   // H*OUT

// Batched transpose for the GEMM weights: dst[c*R + r] = src[r*C + c]
__global__ void transpose_all(const float* __restrict__ wihr,
                              const float* __restrict__ wih0,
                              const float* __restrict__ linw,
                              float* __restrict__ ws) {
    __shared__ float tile[32][33];
    const float* src; float* dst; int R, C;
    switch (blockIdx.z) {
        case 0: case 1: {
            int l = blockIdx.z;
            src = wihr + (size_t)l * H_ * H_;
            dst = ws + OFF_WTI + (size_t)l * H_ * H_;
            R = H_; C = H_; break;
        }
        case 2:
            src = wih0; dst = ws + OFF_WT0; R = H_; C = IN_; break;  // -> [IN][H]
        default:
            src = linw; dst = ws + OFF_WTL; R = OUT_; C = H_; break; // -> [H][OUT]
    }
    int bx = blockIdx.x * 32;
    int by = blockIdx.y * 32;
    if (bx >= C || by >= R) return;
    for (int i = threadIdx.y; i < 32; i += 8) {
        int r = by + i, c = bx + threadIdx.x;
        if (r < R && c < C) tile[i][threadIdx.x] = src[(size_t)r * C + c];
    }
    __syncthreads();
    for (int i = threadIdx.y; i < 32; i += 8) {
        int c = bx + i, r = by + threadIdx.x;
        if (r < R && c < C) dst[(size_t)c * R + r] = tile[threadIdx.x][i];
    }
}

// Pack W_hh (fp32 [l][j][k]) -> Wp dwords [l][kp][j] = half2(W[j][2kp], W[j][2kp+1]), RNE.
__global__ __launch_bounds__(512) void pack_whh(const float* __restrict__ whh,
                                                unsigned int* __restrict__ Wp) {
    const int l = blockIdx.x >> 8;
    const int kp = blockIdx.x & 255;
    const int j = threadIdx.x;
    const float* s = whh + ((size_t)l * H_ + j) * H_ + 2 * kp;
    HU cv;
    cv.h.x = (_Float16)s[0];
    cv.h.y = (_Float16)s[1];
    Wp[((size_t)l * 256 + kp) * H_ + j] = cv.u;
}

// Row-panel GEMM (fp32), verified in R2. In-place safe.
template <int N, int K>
__global__ __launch_bounds__(512) void gemm_panel(const float* In,
                                                  const float* __restrict__ Wt,
                                                  const float* __restrict__ bias,
                                                  float* Out) {
    __shared__ float A[16 * K];
    const int tid = threadIdx.x;
    const size_t m0 = (size_t)blockIdx.x * 16;

    const float4* In4 = (const float4*)(In + m0 * K);
    float4* A4 = (float4*)A;
    for (int i = tid; i < 16 * K / 4; i += 512) A4[i] = In4[i];
    __syncthreads();

    constexpr int TPN = 512 / N;
    constexpr int RPT = 16 / TPN;
    const int j = tid % N;
    const int r0 = (tid / N) * RPT;

    float acc[RPT];
    const float bv = bias[j];
    #pragma unroll
    for (int r = 0; r < RPT; r++) acc[r] = bv;

    for (int k = 0; k < K; k += 4) {
        const float wv0 = Wt[(size_t)(k + 0) * N + j];
        const float wv1 = Wt[(size_t)(k + 1) * N + j];
        const float wv2 = Wt[(size_t)(k + 2) * N + j];
        const float wv3 = Wt[(size_t)(k + 3) * N + j];
        #pragma unroll
        for (int r = 0; r < RPT; r++) {
            const float4 av = *(const float4*)&A[(r0 + r) * K + k];
            acc[r] += av.x * wv0 + av.y * wv1 + av.z * wv2 + av.w * wv3;
        }
    }
    #pragma unroll
    for (int r = 0; r < RPT; r++) Out[(m0 + r0 + r) * N + j] = acc[r];
}

#define MAC8(W0, W1, HV, ACC)                                   \
    do {                                                        \
        HU w0_, w1_, w2_, w3_, w4_, w5_, w6_, w7_;              \
        w0_.u = (W0).x; w1_.u = (W0).y; w2_.u = (W0).z; w3_.u = (W0).w; \
        w4_.u = (W1).x; w5_.u = (W1).y; w6_.u = (W1).z; w7_.u = (W1).w; \
        ACC[0] = fdot2_acc(w0_.h, (HV), ACC[0]);                \
        ACC[1] = fdot2_acc(w1_.h, (HV), ACC[1]);                \
        ACC[2] = fdot2_acc(w2_.h, (HV), ACC[2]);                \
        ACC[3] = fdot2_acc(w3_.h, (HV), ACC[3]);                \
        ACC[4] = fdot2_acc(w4_.h, (HV), ACC[4]);                \
        ACC[5] = fdot2_acc(w5_.h, (HV), ACC[5]);                \
        ACC[6] = fdot2_acc(w6_.h, (HV), ACC[6]);                \
        ACC[7] = fdot2_acc(w7_.h, (HV), ACC[7]);                \
    } while (0)

// Recurrence: 64 blocks (one per batch row) x 512 threads; NO cross-block traffic.
// Thread tid: j-octet jo=tid&63 (j in [8jo,8jo+8)), k-slice ks=tid>>6 (kp in [32ks,32ks+32)).
// Full fp16 W_hh on-CU: kpl 0..23 in VGPRs (48 uint4), kpl 24..31 in LDS (quad-swizzled).
// Per step: 256 fdot2/thread -> LDS k-reduce (padded) -> tanh finalize (j=tid).
__global__ __launch_bounds__(512, 2) void rnn_rec4(float* __restrict__ buf,
                                                   const unsigned int* __restrict__ Wp, // [256][512]
                                                   const float* __restrict__ h0_l,      // [B][H]
                                                   const float* __restrict__ bhh,       // [H]
                                                   float* __restrict__ hout) {          // [B][H]
    __shared__ __align__(16) uint4 WL[512 * 16];         // 128 KB LDS weight quads
    __shared__ __align__(16) float red[8 * 520];         // 16.6 KB padded k-partials
    __shared__ __align__(16) unsigned int hsm2[256];     // h as packed half2 (1 KB)

    const int tid = threadIdx.x;
    const int b   = blockIdx.x;
    const int jo  = tid & 63;
    const int ks  = tid >> 6;          // wave id -> k-slice (wave-uniform h reads)
    const int jbase  = jo * 8;
    const int kpbase = ks * 32;
    const int sw  = tid & 15;          // quad swizzle key

    // ---- stage LDS weight quads (kpl 24..31), per-thread-segment quad-swizzled ----
    #pragma unroll
    for (int q = 0; q < 16; ++q) {
        const int kpl = 24 + (q >> 1);
        const int jh  = (q & 1) * 4;
        WL[tid * 16 + (q ^ sw)] =
            *(const uint4*)(Wp + (size_t)(kpbase + kpl) * H_ + jbase + jh);
    }
    // ---- register weights: kpl 0..23 (48 uint4 = 192 VGPRs, statically indexed) ----
    uint4 wreg[48];
    #pragma unroll
    for (int kpl = 0; kpl < 24; ++kpl) {
        wreg[2 * kpl + 0] = *(const uint4*)(Wp + (size_t)(kpbase + kpl) * H_ + jbase);
        wreg[2 * kpl + 1] = *(const uint4*)(Wp + (size_t)(kpbase + kpl) * H_ + jbase + 4);
    }
    // ---- h(0) ----
    if (tid < 256) {
        const float2 v = *(const float2*)(h0_l + b * H_ + 2 * tid);
        HU cv; cv.h.x = (_Float16)v.x; cv.h.y = (_Float16)v.y;
        hsm2[tid] = cv.u;
    }
    const float bj = bhh[tid];
    __syncthreads();

    for (int t = 0; t < T_; ++t) {
        // prefetch pre-activation (consumed in finalize)
        const float pre = buf[((size_t)t * B_ + b) * H_ + tid];

        float acc[8] = {0.f, 0.f, 0.f, 0.f, 0.f, 0.f, 0.f, 0.f};

        // register part: kpl 0..23, h-pairs loaded 8 at a time (wave-uniform b128)
        #pragma unroll
        for (int g = 0; g < 3; ++g) {
            const uint4* hq = (const uint4*)&hsm2[kpbase + g * 8];
            const uint4 h0v = hq[0], h1v = hq[1];
            unsigned int hp[8] = {h0v.x, h0v.y, h0v.z, h0v.w, h1v.x, h1v.y, h1v.z, h1v.w};
            #pragma unroll
            for (int i = 0; i < 8; ++i) {
                const int kpl = g * 8 + i;
                HU hv; hv.u = hp[i];
                MAC8(wreg[2 * kpl], wreg[2 * kpl + 1], hv.h, acc);
            }
        }
        // LDS part: kpl 24..31
        {
            const uint4* hq = (const uint4*)&hsm2[kpbase + 24];
            const uint4 h0v = hq[0], h1v = hq[1];
            unsigned int hp[8] = {h0v.x, h0v.y, h0v.z, h0v.w, h1v.x, h1v.y, h1v.z, h1v.w};
            #pragma unroll
            for (int i = 0; i < 8; ++i) {
                const uint4 w0 = WL[tid * 16 + ((2 * i + 0) ^ sw)];
                const uint4 w1 = WL[tid * 16 + ((2 * i + 1) ^ sw)];
                HU hv; hv.u = hp[i];
                MAC8(w0, w1, hv.h, acc);
            }
        }

        // k-partials (padded rows: conflict-free finalize reads)
        *(float4*)&red[ks * 520 + jbase]     = make_float4(acc[0], acc[1], acc[2], acc[3]);
        *(float4*)&red[ks * 520 + jbase + 4] = make_float4(acc[4], acc[5], acc[6], acc[7]);
        __syncthreads();  // bar1: partials ready, all hsm2 reads done

        // finalize: j = tid
        float s = pre + bj;
        #pragma unroll
        for (int q = 0; q < 8; ++q) s += red[q * 520 + tid];
        const float hn = tanhf(s);
        buf[((size_t)t * B_ + b) * H_ + tid] = hn;
        ((_Float16*)hsm2)[tid] = (_Float16)hn;
        if (t == T_ - 1) hout[b * H_ + tid] = hn;
        __syncthreads();  // bar2: red consumed + h updated for next step
    }
}

extern "C" void kernel_launch(void* const* d_in, const int* in_sizes, int n_in,
                              void* d_out, int out_size, void* d_ws, size_t ws_size,
                              hipStream_t stream) {
    const float* x      = (const float*)d_in[0];
    const float* h0     = (const float*)d_in[1];
    const float* W_ih0  = (const float*)d_in[2];
    const float* W_ihr  = (const float*)d_in[3];
    const float* W_hh   = (const float*)d_in[4];
    const float* b_ih   = (const float*)d_in[5];
    const float* b_hh   = (const float*)d_in[6];
    const float* lin_W  = (const float*)d_in[7];
    const float* lin_b  = (const float*)d_in[8];
    float* out = (float*)d_out;
    float* ws  = (float*)d_ws;

    float* buf = ws + OFF_BUF;
    unsigned int* Wp = (unsigned int*)(ws + OFF_WHP);
    float* WtI = ws + OFF_WTI;
    float* Wt0 = ws + OFF_WT0;
    float* WtL = ws + OFF_WTL;
    float* h_final = out + (size_t)T_ * B_ * OUT_;  // [L][B][H]

    constexpr int M = T_ * B_;  // 32768 rows

    // 1) prep: transpose GEMM weights (fp32) + pack W_hh to fp16 pairs
    transpose_all<<<dim3(16, 16, 4), dim3(32, 8), 0, stream>>>(W_ihr, W_ih0, lin_W, ws);
    pack_whh<<<3 * 256, 512, 0, stream>>>(W_hh, Wp);

    // 2) layer 0
    gemm_panel<H_, IN_><<<M / 16, 512, 0, stream>>>(x, Wt0, b_ih + 0 * H_, buf);
    rnn_rec4<<<B_, 512, 0, stream>>>(buf, Wp + 0ull * 256 * H_, h0 + 0 * B_ * H_,
                                     b_hh + 0 * H_, h_final + 0 * B_ * H_);

    // 3) layer 1
    gemm_panel<H_, H_><<<M / 16, 512, 0, stream>>>(buf, WtI + 0 * (size_t)H_ * H_,
                                                   b_ih + 1 * H_, buf);
    rnn_rec4<<<B_, 512, 0, stream>>>(buf, Wp + 1ull * 256 * H_, h0 + 1 * B_ * H_,
                                     b_hh + 1 * H_, h_final + 1 * B_ * H_);

    // 4) layer 2
    gemm_panel<H_, H_><<<M / 16, 512, 0, stream>>>(buf, WtI + 1 * (size_t)H_ * H_,
                                                   b_ih + 2 * H_, buf);
    rnn_rec4<<<B_, 512, 0, stream>>>(buf, Wp + 2ull * 256 * H_, h0 + 2 * B_ * H_,
                                     b_hh + 2 * H_, h_final + 2 * B_ * H_);

    // 5) out = ys2 @ lin_W^T + lin_b
    gemm_panel<OUT_, H_><<<M / 16, 512, 0, stream>>>(buf, WtL, lin_b, out);
}

// Round 8
// 3245.672 us; speedup vs baseline: 8.4027x; 1.0551x over previous
//
#include <hip/hip_runtime.h>
#include <math.h>

#define T_ 512
#define B_ 64
#define IN_ 128
#define H_ 512
#define L_ 3
#define OUT_ 128

typedef _Float16 half2_t __attribute__((ext_vector_type(2)));

#if defined(__has_builtin)
#if __has_builtin(__builtin_amdgcn_fdot2)
#define HAVE_FDOT2 1
#endif
#endif

__device__ __forceinline__ float fdot2_acc(half2_t a, half2_t b, float c) {
#ifdef HAVE_FDOT2
    return __builtin_amdgcn_fdot2(a, b, c, false);
#else
    return c + (float)a.x * (float)b.x + (float)a.y * (float)b.y;
#endif
}

union HU { unsigned int u; half2_t h; };

// ---- workspace layout (floats) ----
constexpr size_t OFF_BUF = 0;                            // T*B*H
constexpr size_t OFF_WHP = (size_t)T_ * B_ * H_;         // 3*256*512 dwords (fp16 pairs)
constexpr size_t OFF_WTI = OFF_WHP + 3ull * 256 * H_;    // 2*H*H fp32
constexpr size_t OFF_WT0 = OFF_WTI + 2ull * H_ * H_;     // IN*H
constexpr size_t OFF_WTL = OFF_WT0 + (size_t)IN_ * H_;   // H*OUT

// Batched transpose for the GEMM weights: dst[c*R + r] = src[r*C + c]
__global__ void transpose_all(const float* __restrict__ wihr,
                              const float* __restrict__ wih0,
                              const float* __restrict__ linw,
                              float* __restrict__ ws) {
    __shared__ float tile[32][33];
    const float* src; float* dst; int R, C;
    switch (blockIdx.z) {
        case 0: case 1: {
            int l = blockIdx.z;
            src = wihr + (size_t)l * H_ * H_;
            dst = ws + OFF_WTI + (size_t)l * H_ * H_;
            R = H_; C = H_; break;
        }
        case 2:
            src = wih0; dst = ws + OFF_WT0; R = H_; C = IN_; break;  // -> [IN][H]
        default:
            src = linw; dst = ws + OFF_WTL; R = OUT_; C = H_; break; // -> [H][OUT]
    }
    int bx = blockIdx.x * 32;
    int by = blockIdx.y * 32;
    if (bx >= C || by >= R) return;
    for (int i = threadIdx.y; i < 32; i += 8) {
        int r = by + i, c = bx + threadIdx.x;
        if (r < R && c < C) tile[i][threadIdx.x] = src[(size_t)r * C + c];
    }
    __syncthreads();
    for (int i = threadIdx.y; i < 32; i += 8) {
        int c = bx + i, r = by + threadIdx.x;
        if (r < R && c < C) dst[(size_t)c * R + r] = tile[threadIdx.x][i];
    }
}

// Pack W_hh (fp32 [l][j][k]) -> Wp dwords [l][kp][j] = half2(W[j][2kp], W[j][2kp+1]), RNE.
__global__ __launch_bounds__(512) void pack_whh(const float* __restrict__ whh,
                                                unsigned int* __restrict__ Wp) {
    const int l = blockIdx.x >> 8;
    const int kp = blockIdx.x & 255;
    const int j = threadIdx.x;
    const float* s = whh + ((size_t)l * H_ + j) * H_ + 2 * kp;
    HU cv;
    cv.h.x = (_Float16)s[0];
    cv.h.y = (_Float16)s[1];
    Wp[((size_t)l * 256 + kp) * H_ + j] = cv.u;
}

// Row-panel GEMM (fp32), verified in R2. In-place safe.
template <int N, int K>
__global__ __launch_bounds__(512) void gemm_panel(const float* In,
                                                  const float* __restrict__ Wt,
                                                  const float* __restrict__ bias,
                                                  float* Out) {
    __shared__ float A[16 * K];
    const int tid = threadIdx.x;
    const size_t m0 = (size_t)blockIdx.x * 16;

    const float4* In4 = (const float4*)(In + m0 * K);
    float4* A4 = (float4*)A;
    for (int i = tid; i < 16 * K / 4; i += 512) A4[i] = In4[i];
    __syncthreads();

    constexpr int TPN = 512 / N;
    constexpr int RPT = 16 / TPN;
    const int j = tid % N;
    const int r0 = (tid / N) * RPT;

    float acc[RPT];
    const float bv = bias[j];
    #pragma unroll
    for (int r = 0; r < RPT; r++) acc[r] = bv;

    for (int k = 0; k < K; k += 4) {
        const float wv0 = Wt[(size_t)(k + 0) * N + j];
        const float wv1 = Wt[(size_t)(k + 1) * N + j];
        const float wv2 = Wt[(size_t)(k + 2) * N + j];
        const float wv3 = Wt[(size_t)(k + 3) * N + j];
        #pragma unroll
        for (int r = 0; r < RPT; r++) {
            const float4 av = *(const float4*)&A[(r0 + r) * K + k];
            acc[r] += av.x * wv0 + av.y * wv1 + av.z * wv2 + av.w * wv3;
        }
    }
    #pragma unroll
    for (int r = 0; r < RPT; r++) Out[(m0 + r0 + r) * N + j] = acc[r];
}

#define MAC8(W0, W1, HV, ACC)                                   \
    do {                                                        \
        HU w0_, w1_, w2_, w3_, w4_, w5_, w6_, w7_;              \
        w0_.u = (W0).x; w1_.u = (W0).y; w2_.u = (W0).z; w3_.u = (W0).w; \
        w4_.u = (W1).x; w5_.u = (W1).y; w6_.u = (W1).z; w7_.u = (W1).w; \
        ACC[0] = fdot2_acc(w0_.h, (HV), ACC[0]);                \
        ACC[1] = fdot2_acc(w1_.h, (HV), ACC[1]);                \
        ACC[2] = fdot2_acc(w2_.h, (HV), ACC[2]);                \
        ACC[3] = fdot2_acc(w3_.h, (HV), ACC[3]);                \
        ACC[4] = fdot2_acc(w4_.h, (HV), ACC[4]);                \
        ACC[5] = fdot2_acc(w5_.h, (HV), ACC[5]);                \
        ACC[6] = fdot2_acc(w6_.h, (HV), ACC[6]);                \
        ACC[7] = fdot2_acc(w7_.h, (HV), ACC[7]);                \
    } while (0)

// Recurrence: 64 blocks (one per batch row) x 512 threads; NO cross-block traffic.
// Thread tid: j-octet jo=tid&63 (j in [8jo,8jo+8)), k-slice ks=tid>>6 (kp in [32ks,32ks+32)).
// fp16 W_hh on-CU: kp-local 0..23 in VGPR/AGPR (48 uint4), 24..31 in LDS.
// LDS weight layout [((lkp*2+h)*8+ks)*64 + jo]: a wave's 64 lanes read 64
// CONSECUTIVE uint4s -> conflict-free ds_read_b128 (fix for R5's 8-way).
// red swizzle = rec3's verified scheme (0 conflicts in R4 profile).
__global__ __launch_bounds__(512, 2) void rnn_rec5(float* __restrict__ buf,
                                                   const unsigned int* __restrict__ Wp, // [256][512]
                                                   const float* __restrict__ h0_l,      // [B][H]
                                                   const float* __restrict__ bhh,       // [H]
                                                   float* __restrict__ hout) {          // [B][H]
    __shared__ __align__(16) uint4 WL[8 * 2 * 8 * 64];   // 128 KB  [lkp][h][ks][jo]
    __shared__ __align__(16) float4 red4[8 * 128];       // 16 KB   swizzled k-partials
    __shared__ __align__(16) unsigned int hsm2[256];     // h as packed half2 (1 KB)

    const int tid = threadIdx.x;
    const int b   = blockIdx.x;
    const int jo  = tid & 63;
    const int ks  = tid >> 6;          // wave id -> k-slice (wave-uniform h reads)
    const int jbase  = jo * 8;
    const int kpbase = ks * 32;

    // ---- stage LDS weight quads (kp-local 24..31), conflict-free layout ----
    #pragma unroll
    for (int lkp = 0; lkp < 8; ++lkp) {
        #pragma unroll
        for (int h = 0; h < 2; ++h) {
            WL[((lkp * 2 + h) * 8 + ks) * 64 + jo] =
                *(const uint4*)(Wp + (size_t)(kpbase + 24 + lkp) * H_ + jbase + h * 4);
        }
    }
    // ---- register weights: kp-local 0..23 (48 uint4, statically indexed) ----
    uint4 wreg[48];
    #pragma unroll
    for (int kpl = 0; kpl < 24; ++kpl) {
        wreg[2 * kpl + 0] = *(const uint4*)(Wp + (size_t)(kpbase + kpl) * H_ + jbase);
        wreg[2 * kpl + 1] = *(const uint4*)(Wp + (size_t)(kpbase + kpl) * H_ + jbase + 4);
    }
    // ---- h(0) ----
    if (tid < 256) {
        const float2 v = *(const float2*)(h0_l + b * H_ + 2 * tid);
        HU cv; cv.h.x = (_Float16)v.x; cv.h.y = (_Float16)v.y;
        hsm2[tid] = cv.u;
    }
    const float bj = bhh[tid];
    const int swz = (jo >> 2) & 7;           // write-side swizzle key
    const int rf  = (tid >> 2) ^ ((tid >> 5) & 7);  // read-side f (finalize, j = tid)
    const int re  = tid & 3;
    __syncthreads();

    for (int t = 0; t < T_; ++t) {
        // prefetch pre-activation (consumed in finalize)
        const float pre = buf[((size_t)t * B_ + b) * H_ + tid];

        float acc[8] = {0.f, 0.f, 0.f, 0.f, 0.f, 0.f, 0.f, 0.f};

        // register part: kp-local 0..23, h-pairs read 8 at a time (wave-uniform b128)
        #pragma unroll
        for (int g = 0; g < 3; ++g) {
            const uint4* hq = (const uint4*)&hsm2[kpbase + g * 8];
            const uint4 h0v = hq[0], h1v = hq[1];
            unsigned int hp[8] = {h0v.x, h0v.y, h0v.z, h0v.w, h1v.x, h1v.y, h1v.z, h1v.w};
            #pragma unroll
            for (int i = 0; i < 8; ++i) {
                const int kpl = g * 8 + i;
                HU hv; hv.u = hp[i];
                MAC8(wreg[2 * kpl], wreg[2 * kpl + 1], hv.h, acc);
            }
        }
        // LDS part: kp-local 24..31 (conflict-free reads)
        {
            const uint4* hq = (const uint4*)&hsm2[kpbase + 24];
            const uint4 h0v = hq[0], h1v = hq[1];
            unsigned int hp[8] = {h0v.x, h0v.y, h0v.z, h0v.w, h1v.x, h1v.y, h1v.z, h1v.w};
            #pragma unroll
            for (int i = 0; i < 8; ++i) {
                const uint4 w0 = WL[((i * 2 + 0) * 8 + ks) * 64 + jo];
                const uint4 w1 = WL[((i * 2 + 1) * 8 + ks) * 64 + jo];
                HU hv; hv.u = hp[i];
                MAC8(w0, w1, hv.h, acc);
            }
        }

        // k-partials, swizzled rows of 128 float4 (write <=2-way, read conflict-free)
        red4[ks * 128 + ((jo * 2 + 0) ^ swz)] = make_float4(acc[0], acc[1], acc[2], acc[3]);
        red4[ks * 128 + ((jo * 2 + 1) ^ swz)] = make_float4(acc[4], acc[5], acc[6], acc[7]);
        __syncthreads();  // bar1: partials ready, all hsm2 reads done

        // finalize: j = tid
        const float* redf = (const float*)red4;
        float s = pre + bj;
        #pragma unroll
        for (int q = 0; q < 8; ++q) s += redf[(q * 128 + rf) * 4 + re];
        const float hn = tanhf(s);
        buf[((size_t)t * B_ + b) * H_ + tid] = hn;
        ((_Float16*)hsm2)[tid] = (_Float16)hn;
        if (t == T_ - 1) hout[b * H_ + tid] = hn;
        __syncthreads();  // bar2: red consumed + h updated for next step
    }
}

extern "C" void kernel_launch(void* const* d_in, const int* in_sizes, int n_in,
                              void* d_out, int out_size, void* d_ws, size_t ws_size,
                              hipStream_t stream) {
    const float* x      = (const float*)d_in[0];
    const float* h0     = (const float*)d_in[1];
    const float* W_ih0  = (const float*)d_in[2];
    const float* W_ihr  = (const float*)d_in[3];
    const float* W_hh   = (const float*)d_in[4];
    const float* b_ih   = (const float*)d_in[5];
    const float* b_hh   = (const float*)d_in[6];
    const float* lin_W  = (const float*)d_in[7];
    const float* lin_b  = (const float*)d_in[8];
    float* out = (float*)d_out;
    float* ws  = (float*)d_ws;

    float* buf = ws + OFF_BUF;
    unsigned int* Wp = (unsigned int*)(ws + OFF_WHP);
    float* WtI = ws + OFF_WTI;
    float* Wt0 = ws + OFF_WT0;
    float* WtL = ws + OFF_WTL;
    float* h_final = out + (size_t)T_ * B_ * OUT_;  // [L][B][H]

    constexpr int M = T_ * B_;  // 32768 rows

    // 1) prep: transpose GEMM weights (fp32) + pack W_hh to fp16 pairs
    transpose_all<<<dim3(16, 16, 4), dim3(32, 8), 0, stream>>>(W_ihr, W_ih0, lin_W, ws);
    pack_whh<<<3 * 256, 512, 0, stream>>>(W_hh, Wp);

    // 2) layer 0
    gemm_panel<H_, IN_><<<M / 16, 512, 0, stream>>>(x, Wt0, b_ih + 0 * H_, buf);
    rnn_rec5<<<B_, 512, 0, stream>>>(buf, Wp + 0ull * 256 * H_, h0 + 0 * B_ * H_,
                                     b_hh + 0 * H_, h_final + 0 * B_ * H_);

    // 3) layer 1
    gemm_panel<H_, H_><<<M / 16, 512, 0, stream>>>(buf, WtI + 0 * (size_t)H_ * H_,
                                                   b_ih + 1 * H_, buf);
    rnn_rec5<<<B_, 512, 0, stream>>>(buf, Wp + 1ull * 256 * H_, h0 + 1 * B_ * H_,
                                     b_hh + 1 * H_, h_final + 1 * B_ * H_);

    // 4) layer 2
    gemm_panel<H_, H_><<<M / 16, 512, 0, stream>>>(buf, WtI + 1 * (size_t)H_ * H_,
                                                   b_ih + 2 * H_, buf);
    rnn_rec5<<<B_, 512, 0, stream>>>(buf, Wp + 2ull * 256 * H_, h0 + 2 * B_ * H_,
                                     b_hh + 2 * H_, h_final + 2 * B_ * H_);

    // 5) out = ys2 @ lin_W^T + lin_b
    gemm_panel<OUT_, H_><<<M / 16, 512, 0, stream>>>(buf, WtL, lin_b, out);
}

// Round 9
// 2409.529 us; speedup vs baseline: 11.3185x; 1.3470x over previous
//
#include <hip/hip_runtime.h>
#include <math.h>

#define T_ 512
#define B_ 64
#define IN_ 128
#define H_ 512
#define L_ 3
#define OUT_ 128

typedef _Float16 half2_t __attribute__((ext_vector_type(2)));
typedef _Float16 f16x8_t __attribute__((ext_vector_type(8)));
typedef float f32x4_t __attribute__((ext_vector_type(4)));

#if defined(__has_builtin)
#if __has_builtin(__builtin_amdgcn_fdot2)
#define HAVE_FDOT2 1
#endif
#endif

__device__ __forceinline__ float fdot2_acc(half2_t a, half2_t b, float c) {
#ifdef HAVE_FDOT2
    return __builtin_amdgcn_fdot2(a, b, c, false);
#else
    return c + (float)a.x * (float)b.x + (float)a.y * (float)b.y;
#endif
}

union HU { unsigned int u; half2_t h; };
union BU { uint4 u; f16x8_t h; };

// ---- workspace layout (dwords) ----
constexpr size_t OFF_BUF = 0;                           // T*B*H = 16,777,216
constexpr size_t OFF_WHP = (size_t)T_ * B_ * H_;        // 3*256*512 = 393,216 (rec fp16 pairs)
constexpr size_t OFF_BP0 = OFF_WHP + 3ull * 256 * H_;   // W_ih0 frags: 32nt*4kt*64*4 = 32,768
constexpr size_t OFF_BPR = OFF_BP0 + 32768;             // W_ihr frags: 2 * 32*16*64*4 = 262,144
constexpr size_t OFF_BPL = OFF_BPR + 262144;            // lin_W frags: 8*16*64*4 = 32,768
// total ≈ 17.5M dwords ≈ 67 MB

// Pack W_hh (fp32 [l][j][k]) -> Wp dwords [l][kp][j] = half2(W[j][2kp], W[j][2kp+1]), RNE.
__global__ __launch_bounds__(512) void pack_whh(const float* __restrict__ whh,
                                                unsigned int* __restrict__ Wp) {
    const int l = blockIdx.x >> 8;
    const int kp = blockIdx.x & 255;
    const int j = threadIdx.x;
    const float* s = whh + ((size_t)l * H_ + j) * H_ + 2 * kp;
    HU cv;
    cv.h.x = (_Float16)s[0];
    cv.h.y = (_Float16)s[1];
    Wp[((size_t)l * 256 + kp) * H_ + j] = cv.u;
}

// Pack a weight matrix W[N][Kdim] (fp32, row-major) into MFMA B-fragments:
// Bp[(nt*KT + kt)*64 + lane] = 8 f16 of W^T[k0..k0+8][n] = W[n][k0..k0+8],
// n = nt*16 + (lane&15), k0 = kt*32 + (lane>>4)*8.  One block per (nt,kt).
__global__ __launch_bounds__(64) void pack_bfrag(const float* __restrict__ W,
                                                 uint4* __restrict__ Bp,
                                                 int KT, int Kdim) {
    const int t  = blockIdx.x;
    const int kt = t % KT;
    const int nt = t / KT;
    const int l  = threadIdx.x;
    const int n  = nt * 16 + (l & 15);
    const int k0 = kt * 32 + (l >> 4) * 8;
    const float* s = W + (size_t)n * Kdim + k0;
    BU cv;
    #pragma unroll
    for (int i = 0; i < 8; ++i) cv.h[i] = (_Float16)s[i];
    Bp[(size_t)t * 64 + l] = cv.u;
}

// MFMA GEMM: Out[m][n] = sum_k In[m][k]*W[n][k] + bias[n], In fp32 -> f16 staged.
// BM=32 rows/block, 256 threads (4 waves): wave w -> rows (w&1)*16, cols (w>>1)*(N/2).
// A staged in LDS as 8-f16 slots, XOR-swizzled by row to avoid row-stride conflicts.
// In-place safe: all In reads staged before barrier; writes after full K loop;
// rows exclusive per block.
template <int N, int K>
__global__ __launch_bounds__(256) void gemm_mfma(const float* In,
                                                 const uint4* __restrict__ Bp,
                                                 const float* __restrict__ bias,
                                                 float* Out) {
    constexpr int KT    = K / 32;       // k-tiles
    constexpr int SLOTS = K / 8;        // 8-f16 slots per row
    constexpr int NTW   = N / 32;       // n-tiles per wave (half of N/16)
    constexpr int PASS_NT = (NTW > 8) ? 8 : NTW;
    constexpr int NPASS   = NTW / PASS_NT;

    __shared__ uint4 Ah[32 * SLOTS];

    const int tid = threadIdx.x;
    const int l   = tid & 63;
    const int w   = tid >> 6;
    const size_t m0 = (size_t)blockIdx.x * 32;

    // ---- stage A: fp32 -> f16 slots, swizzled ----
    constexpr int TSLOTS = 32 * SLOTS / 256;
    #pragma unroll
    for (int i = 0; i < TSLOTS; ++i) {
        const int s   = tid + i * 256;
        const int row = s / SLOTS;
        const int sl  = s % SLOTS;
        const float* src = In + (m0 + row) * K + sl * 8;
        BU cv;
        #pragma unroll
        for (int j = 0; j < 8; ++j) cv.h[j] = (_Float16)src[j];
        Ah[row * SLOTS + (sl ^ (row & 7))] = cv.u;
    }
    __syncthreads();

    const int rw = (w & 1) * 16;
    const int cw = (w >> 1) * (N / 2);
    const int arow = rw + (l & 15);
    const int ag   = l >> 4;

    #pragma unroll
    for (int p = 0; p < NPASS; ++p) {
        f32x4_t acc[PASS_NT];
        #pragma unroll
        for (int nt = 0; nt < PASS_NT; ++nt) acc[nt] = (f32x4_t){0.f, 0.f, 0.f, 0.f};

        for (int kt = 0; kt < KT; ++kt) {
            BU av; av.u = Ah[arow * SLOTS + ((kt * 4 + ag) ^ (arow & 7))];
            #pragma unroll
            for (int nt = 0; nt < PASS_NT; ++nt) {
                const int ntg = (cw >> 4) + p * PASS_NT + nt;
                BU bv; bv.u = Bp[(size_t)(ntg * KT + kt) * 64 + l];
                acc[nt] = __builtin_amdgcn_mfma_f32_16x16x32_f16(av.h, bv.h, acc[nt], 0, 0, 0);
            }
        }
        // epilogue: D col = lane&15, row = (lane>>4)*4 + reg  (m89-verified)
        #pragma unroll
        for (int nt = 0; nt < PASS_NT; ++nt) {
            const int colg = cw + (p * PASS_NT + nt) * 16 + (l & 15);
            const float bv = bias[colg];
            #pragma unroll
            for (int r = 0; r < 4; ++r) {
                const int rowg = rw + (l >> 4) * 4 + r;
                Out[(m0 + rowg) * N + colg] = acc[nt][r] + bv;
            }
        }
    }
}

#define MAC8(W0, W1, HV, ACC)                                   \
    do {                                                        \
        HU w0_, w1_, w2_, w3_, w4_, w5_, w6_, w7_;              \
        w0_.u = (W0).x; w1_.u = (W0).y; w2_.u = (W0).z; w3_.u = (W0).w; \
        w4_.u = (W1).x; w5_.u = (W1).y; w6_.u = (W1).z; w7_.u = (W1).w; \
        ACC[0] = fdot2_acc(w0_.h, (HV), ACC[0]);                \
        ACC[1] = fdot2_acc(w1_.h, (HV), ACC[1]);                \
        ACC[2] = fdot2_acc(w2_.h, (HV), ACC[2]);                \
        ACC[3] = fdot2_acc(w3_.h, (HV), ACC[3]);                \
        ACC[4] = fdot2_acc(w4_.h, (HV), ACC[4]);                \
        ACC[5] = fdot2_acc(w5_.h, (HV), ACC[5]);                \
        ACC[6] = fdot2_acc(w6_.h, (HV), ACC[6]);                \
        ACC[7] = fdot2_acc(w7_.h, (HV), ACC[7]);                \
    } while (0)

// Recurrence: UNCHANGED from R8's measured kernel (757 us/layer, 0 bank conflicts).
__global__ __launch_bounds__(512, 2) void rnn_rec5(float* __restrict__ buf,
                                                   const unsigned int* __restrict__ Wp, // [256][512]
                                                   const float* __restrict__ h0_l,      // [B][H]
                                                   const float* __restrict__ bhh,       // [H]
                                                   float* __restrict__ hout) {          // [B][H]
    __shared__ __align__(16) uint4 WL[8 * 2 * 8 * 64];   // 128 KB  [lkp][h][ks][jo]
    __shared__ __align__(16) float4 red4[8 * 128];       // 16 KB   swizzled k-partials
    __shared__ __align__(16) unsigned int hsm2[256];     // h as packed half2 (1 KB)

    const int tid = threadIdx.x;
    const int b   = blockIdx.x;
    const int jo  = tid & 63;
    const int ks  = tid >> 6;          // wave id -> k-slice (wave-uniform h reads)
    const int jbase  = jo * 8;
    const int kpbase = ks * 32;

    // ---- stage LDS weight quads (kp-local 24..31), conflict-free layout ----
    #pragma unroll
    for (int lkp = 0; lkp < 8; ++lkp) {
        #pragma unroll
        for (int h = 0; h < 2; ++h) {
            WL[((lkp * 2 + h) * 8 + ks) * 64 + jo] =
                *(const uint4*)(Wp + (size_t)(kpbase + 24 + lkp) * H_ + jbase + h * 4);
        }
    }
    // ---- register weights: kp-local 0..23 (48 uint4, statically indexed) ----
    uint4 wreg[48];
    #pragma unroll
    for (int kpl = 0; kpl < 24; ++kpl) {
        wreg[2 * kpl + 0] = *(const uint4*)(Wp + (size_t)(kpbase + kpl) * H_ + jbase);
        wreg[2 * kpl + 1] = *(const uint4*)(Wp + (size_t)(kpbase + kpl) * H_ + jbase + 4);
    }
    // ---- h(0) ----
    if (tid < 256) {
        const float2 v = *(const float2*)(h0_l + b * H_ + 2 * tid);
        HU cv; cv.h.x = (_Float16)v.x; cv.h.y = (_Float16)v.y;
        hsm2[tid] = cv.u;
    }
    const float bj = bhh[tid];
    const int swz = (jo >> 2) & 7;           // write-side swizzle key
    const int rf  = (tid >> 2) ^ ((tid >> 5) & 7);  // read-side f (finalize, j = tid)
    const int re  = tid & 3;
    __syncthreads();

    for (int t = 0; t < T_; ++t) {
        // prefetch pre-activation (consumed in finalize)
        const float pre = buf[((size_t)t * B_ + b) * H_ + tid];

        float acc[8] = {0.f, 0.f, 0.f, 0.f, 0.f, 0.f, 0.f, 0.f};

        // register part: kp-local 0..23, h-pairs read 8 at a time (wave-uniform b128)
        #pragma unroll
        for (int g = 0; g < 3; ++g) {
            const uint4* hq = (const uint4*)&hsm2[kpbase + g * 8];
            const uint4 h0v = hq[0], h1v = hq[1];
            unsigned int hp[8] = {h0v.x, h0v.y, h0v.z, h0v.w, h1v.x, h1v.y, h1v.z, h1v.w};
            #pragma unroll
            for (int i = 0; i < 8; ++i) {
                const int kpl = g * 8 + i;
                HU hv; hv.u = hp[i];
                MAC8(wreg[2 * kpl], wreg[2 * kpl + 1], hv.h, acc);
            }
        }
        // LDS part: kp-local 24..31 (conflict-free reads)
        {
            const uint4* hq = (const uint4*)&hsm2[kpbase + 24];
            const uint4 h0v = hq[0], h1v = hq[1];
            unsigned int hp[8] = {h0v.x, h0v.y, h0v.z, h0v.w, h1v.x, h1v.y, h1v.z, h1v.w};
            #pragma unroll
            for (int i = 0; i < 8; ++i) {
                const uint4 w0 = WL[((i * 2 + 0) * 8 + ks) * 64 + jo];
                const uint4 w1 = WL[((i * 2 + 1) * 8 + ks) * 64 + jo];
                HU hv; hv.u = hp[i];
                MAC8(w0, w1, hv.h, acc);
            }
        }

        // k-partials, swizzled rows of 128 float4 (write <=2-way, read conflict-free)
        red4[ks * 128 + ((jo * 2 + 0) ^ swz)] = make_float4(acc[0], acc[1], acc[2], acc[3]);
        red4[ks * 128 + ((jo * 2 + 1) ^ swz)] = make_float4(acc[4], acc[5], acc[6], acc[7]);
        __syncthreads();  // bar1: partials ready, all hsm2 reads done

        // finalize: j = tid
        const float* redf = (const float*)red4;
        float s = pre + bj;
        #pragma unroll
        for (int q = 0; q < 8; ++q) s += redf[(q * 128 + rf) * 4 + re];
        const float hn = tanhf(s);
        buf[((size_t)t * B_ + b) * H_ + tid] = hn;
        ((_Float16*)hsm2)[tid] = (_Float16)hn;
        if (t == T_ - 1) hout[b * H_ + tid] = hn;
        __syncthreads();  // bar2: red consumed + h updated for next step
    }
}

extern "C" void kernel_launch(void* const* d_in, const int* in_sizes, int n_in,
                              void* d_out, int out_size, void* d_ws, size_t ws_size,
                              hipStream_t stream) {
    const float* x      = (const float*)d_in[0];
    const float* h0     = (const float*)d_in[1];
    const float* W_ih0  = (const float*)d_in[2];
    const float* W_ihr  = (const float*)d_in[3];
    const float* W_hh   = (const float*)d_in[4];
    const float* b_ih   = (const float*)d_in[5];
    const float* b_hh   = (const float*)d_in[6];
    const float* lin_W  = (const float*)d_in[7];
    const float* lin_b  = (const float*)d_in[8];
    float* out = (float*)d_out;
    float* ws  = (float*)d_ws;

    float* buf = ws + OFF_BUF;
    unsigned int* Wp = (unsigned int*)(ws + OFF_WHP);
    uint4* Bp0 = (uint4*)(ws + OFF_BP0);
    uint4* BpR = (uint4*)(ws + OFF_BPR);
    uint4* BpL = (uint4*)(ws + OFF_BPL);
    float* h_final = out + (size_t)T_ * B_ * OUT_;  // [L][B][H]

    constexpr int M = T_ * B_;  // 32768 rows
    constexpr int GB = M / 32;  // 1024 gemm blocks

    // 1) prep: pack W_hh (rec) + MFMA B-fragments for all GEMM weights
    pack_whh<<<3 * 256, 512, 0, stream>>>(W_hh, Wp);
    pack_bfrag<<<32 * 4, 64, 0, stream>>>(W_ih0, Bp0, 4, IN_);                  // [512][128]
    pack_bfrag<<<32 * 16, 64, 0, stream>>>(W_ihr, BpR, 16, H_);                 // layer1 [512][512]
    pack_bfrag<<<32 * 16, 64, 0, stream>>>(W_ihr + (size_t)H_ * H_, BpR + 32768, 16, H_); // layer2
    pack_bfrag<<<8 * 16, 64, 0, stream>>>(lin_W, BpL, 16, H_);                  // [128][512]

    // 2) layer 0
    gemm_mfma<H_, IN_><<<GB, 256, 0, stream>>>(x, Bp0, b_ih + 0 * H_, buf);
    rnn_rec5<<<B_, 512, 0, stream>>>(buf, Wp + 0ull * 256 * H_, h0 + 0 * B_ * H_,
                                     b_hh + 0 * H_, h_final + 0 * B_ * H_);

    // 3) layer 1
    gemm_mfma<H_, H_><<<GB, 256, 0, stream>>>(buf, BpR, b_ih + 1 * H_, buf);
    rnn_rec5<<<B_, 512, 0, stream>>>(buf, Wp + 1ull * 256 * H_, h0 + 1 * B_ * H_,
                                     b_hh + 1 * H_, h_final + 1 * B_ * H_);

    // 4) layer 2
    gemm_mfma<H_, H_><<<GB, 256, 0, stream>>>(buf, BpR + 32768, b_ih + 2 * H_, buf);
    rnn_rec5<<<B_, 512, 0, stream>>>(buf, Wp + 2ull * 256 * H_, h0 + 2 * B_ * H_,
                                     b_hh + 2 * H_, h_final + 2 * B_ * H_);

    // 5) out = ys2 @ lin_W^T + lin_b
    gemm_mfma<OUT_, H_><<<GB, 256, 0, stream>>>(buf, BpL, lin_b, out);
}